// Round 5
// baseline (1819.439 us; speedup 1.0000x reference)
//
#include <hip/hip_runtime.h>
#include <hip/hip_bf16.h>

#define DEV __device__ __forceinline__

typedef __attribute__((ext_vector_type(8))) short short8;
typedef __attribute__((ext_vector_type(4))) float f32x4;

DEV unsigned short f2bf(float f){
  unsigned int u = __builtin_bit_cast(unsigned int, f);
  u += 0x7FFFu + ((u >> 16) & 1u);
  return (unsigned short)(u >> 16);
}

DEV void gld_lds16(const void* g, void* l){
  __builtin_amdgcn_global_load_lds((const __attribute__((address_space(1))) void*)g,
                                   (__attribute__((address_space(3))) void*)l, 16, 0, 0);
}

// ---------------- embedding: h = wte[x] + pos ----------------
__global__ void k_embed(const int* __restrict__ x, const float* __restrict__ wte,
                        const float* __restrict__ pos, float* __restrict__ h){
  int i = blockIdx.x * 256 + threadIdx.x;           // total 8192*768
  int row = i / 768, d = i - row * 768;
  int s = row & 1023;
  h[i] = wte[x[row] * 768 + d] + pos[s * 768 + d];
}

// ---------------- layernorm (f32 in) -> bf16 out ----------------
__global__ void k_ln(const float* __restrict__ src, const float* __restrict__ g,
                     const float* __restrict__ b, unsigned short* __restrict__ out){
  int row = blockIdx.x, t = threadIdx.x;
  const float* p = src + (size_t)row * 768;
  float v0 = p[t], v1 = p[t + 256], v2 = p[t + 512];
  float s = v0 + v1 + v2;
  float sq = v0 * v0 + v1 * v1 + v2 * v2;
  #pragma unroll
  for(int m = 32; m >= 1; m >>= 1){ s += __shfl_xor(s, m); sq += __shfl_xor(sq, m); }
  __shared__ float red[8];
  int w = t >> 6;
  if((t & 63) == 0){ red[w] = s; red[4 + w] = sq; }
  __syncthreads();
  float S  = red[0] + red[1] + red[2] + red[3];
  float SQ = red[4] + red[5] + red[6] + red[7];
  float mu  = S * (1.0f / 768.0f);
  float var = SQ * (1.0f / 768.0f) - mu * mu;
  float inv = rsqrtf(var + 1e-5f);
  unsigned short* o = out + (size_t)row * 768;
  o[t]       = f2bf((v0 - mu) * inv * g[t]       + b[t]);
  o[t + 256] = f2bf((v1 - mu) * inv * g[t + 256] + b[t + 256]);
  o[t + 512] = f2bf((v2 - mu) * inv * g[t + 512] + b[t + 512]);
}

// ---------------- tiled transpose f32[R][C] -> bf16 dst[C][R] ----------------
DEV void tr_tile(float (*tl)[33], const float* __restrict__ src, unsigned short* __restrict__ dst,
                 int R, int C, int tx, int ty, int tid){
  int lx = tid & 31, ly = tid >> 5;                 // 32 x 8
  int r0 = ty * 32, c0 = tx * 32;
  #pragma unroll
  for(int i = 0; i < 4; i++) tl[ly + 8*i][lx] = src[(size_t)(r0 + ly + 8*i) * C + (c0 + lx)];
  __syncthreads();
  #pragma unroll
  for(int i = 0; i < 4; i++) dst[(size_t)(c0 + ly + 8*i) * R + (r0 + lx)] = f2bf(tl[lx][ly + 8*i]);
}

__global__ void k_convert_layer(const float* __restrict__ wq, const float* __restrict__ wk,
                                const float* __restrict__ wv, const float* __restrict__ w1,
                                const float* __restrict__ w2, const float* __restrict__ bq,
                                const float* __restrict__ bk, const float* __restrict__ bv,
                                unsigned short* __restrict__ wqkv_t, unsigned short* __restrict__ w1_t,
                                unsigned short* __restrict__ w2_t, float* __restrict__ qkv_bias){
  __shared__ float tl[32][33];
  int bid = blockIdx.x, tid = threadIdx.x;
  if(bid < 1728){
    int which = bid / 576, t = bid - which * 576;   // 24x24 tiles of 768x768
    const float* src = which == 0 ? wq : which == 1 ? wk : wv;
    tr_tile(tl, src, wqkv_t + (size_t)which * 589824, 768, 768, t % 24, t / 24, tid);
  } else if(bid < 1728 + 2304){
    int t = bid - 1728;                             // 96x24 tiles of 768x3072
    tr_tile(tl, w1, w1_t, 768, 3072, t % 96, t / 96, tid);
  } else if(bid < 1728 + 4608){
    int t = bid - 4032;                             // 24x96 tiles of 3072x768
    tr_tile(tl, w2, w2_t, 3072, 768, t % 24, t / 24, tid);
  } else {
    for(int i = tid; i < 768; i += 256){
      qkv_bias[i] = bq[i]; qkv_bias[768 + i] = bk[i]; qkv_bias[1536 + i] = bv[i];
    }
  }
}

__global__ void k_transpose(const float* __restrict__ src, unsigned short* __restrict__ dst,
                            int R, int C){
  __shared__ float tl[32][33];
  int nx = C / 32;
  tr_tile(tl, src, dst, R, C, blockIdx.x % nx, blockIdx.x / nx, threadIdx.x);
}

// ---------------- bf16 GEMM: C[M,N] = A[M,K] * Bt[N,K]^T  (+ fused epilogue) ----------------
// m97 structure: 128x128 tile, BK=64, 4 waves, single-buffer 2-barrier loop,
// global_load_lds width 16 with pre-swizzled source (T2 XOR on 16B chunks).
// T1: XCD-chunked block swizzle (bm-major chunks per XCD; requires nwg%8==0).
// Split-K via gridDim.z: each z does K/nz, combining through device-scope atomicAdd
// (EPI 2 and 3); bias applied by z==0 only.
// EPI 0: +bias, split into q/k/v [B*H, S, 64] bf16
// EPI 1: +bias, fast GELU, bf16 out [M,N]
// EPI 2: +bias, atomicAdd into h (residual)
// EPI 3: atomicAdd into f32 logits [M,512] (zero-initialized by caller)
template<int EPI>
__global__ __launch_bounds__(256)
void k_gemm(const unsigned short* __restrict__ A, const unsigned short* __restrict__ Bt,
            const float* __restrict__ bias, int K,
            float* __restrict__ fout, unsigned short* __restrict__ o0,
            unsigned short* __restrict__ o1, unsigned short* __restrict__ o2){
  __shared__ unsigned short As[128 * 64];
  __shared__ unsigned short Bs[128 * 64];
  int tid = threadIdx.x, w = tid >> 6, lane = tid & 63;
  int nbx = gridDim.x;
  int bid = blockIdx.y * nbx + blockIdx.x;
  int cpx = (nbx * gridDim.y) >> 3;
  int sid = (bid & 7) * cpx + (bid >> 3);       // XCD k owns sids [k*cpx,(k+1)*cpx)
  int bm = sid / nbx, bn = sid - bm * nbx;      // bm-major within chunk -> A-panel/XCD locality
  int zz = blockIdx.z;
  int kLen = K / (int)gridDim.z, k0 = zz * kLen;
  int N = nbx * 128;
  int wr = w >> 1, wc = w & 1;
  f32x4 acc[4][4] = {};
  // staging geometry: instr i covers LDS bytes [(i*4+w)*1024, +1024)
  int rowA[4], colA[4];
  #pragma unroll
  for(int i = 0; i < 4; i++){
    int o = ((i * 4 + w) << 10) + (lane << 4);
    int r = o >> 7;                 // tile row (128B rows)
    int ch = (o >> 4) & 7;          // LDS 16B chunk within row
    rowA[i] = r;
    colA[i] = ((ch ^ (r & 7)) << 3);  // source element offset (swizzled)
  }
  const size_t aBase = (size_t)bm * 128;
  const size_t bBase = (size_t)bn * 128;
  for(int kt = k0; kt < k0 + kLen; kt += 64){
    #pragma unroll
    for(int i = 0; i < 4; i++){
      gld_lds16(A  + (aBase + rowA[i]) * K + kt + colA[i], (char*)As + ((i * 4 + w) << 10));
      gld_lds16(Bt + (bBase + rowA[i]) * K + kt + colA[i], (char*)Bs + ((i * 4 + w) << 10));
    }
    __syncthreads();
    #pragma unroll
    for(int s = 0; s < 2; s++){
      short8 af[4], bfr[4];
      #pragma unroll
      for(int m = 0; m < 4; m++){
        int r = wr * 64 + m * 16 + (lane & 15);
        int ch = s * 4 + (lane >> 4);
        af[m] = *(const short8*)(As + r * 64 + ((ch ^ (r & 7)) << 3));
      }
      #pragma unroll
      for(int n = 0; n < 4; n++){
        int r = wc * 64 + n * 16 + (lane & 15);
        int ch = s * 4 + (lane >> 4);
        bfr[n] = *(const short8*)(Bs + r * 64 + ((ch ^ (r & 7)) << 3));
      }
      #pragma unroll
      for(int m = 0; m < 4; m++)
        #pragma unroll
        for(int n = 0; n < 4; n++)
          acc[m][n] = __builtin_amdgcn_mfma_f32_16x16x32_bf16(af[m], bfr[n], acc[m][n], 0, 0, 0);
    }
    __syncthreads();
  }
  int r0 = bm * 128 + wr * 64 + ((lane >> 4) << 2);
  int c0 = bn * 128 + wc * 64 + (lane & 15);
  if(EPI == 0){
    unsigned short* dstn[4];
    float bv4[4];
    #pragma unroll
    for(int n = 0; n < 4; n++){
      int col = c0 + n * 16;
      bv4[n] = bias[col];
      int which = col / 768, cc = col - which * 768;
      int hd = cc >> 6, dl = cc & 63;
      unsigned short* dst = which == 0 ? o0 : which == 1 ? o1 : o2;
      dstn[n] = dst + (size_t)hd * 65536 + dl;
    }
    #pragma unroll
    for(int m = 0; m < 4; m++){
      #pragma unroll
      for(int j = 0; j < 4; j++){
        int row = r0 + m * 16 + j;
        int bb = row >> 10, sp = row & 1023;
        size_t ro = ((size_t)bb * 12288 + sp) * 64;
        #pragma unroll
        for(int n = 0; n < 4; n++)
          dstn[n][ro] = f2bf(acc[m][n][j] + bv4[n]);
      }
    }
  } else {
    float bv4[4];
    #pragma unroll
    for(int n = 0; n < 4; n++)
      bv4[n] = (EPI == 3 || zz != 0) ? 0.0f : bias[c0 + n * 16];
    #pragma unroll
    for(int m = 0; m < 4; m++){
      #pragma unroll
      for(int j = 0; j < 4; j++){
        int row = r0 + m * 16 + j;
        #pragma unroll
        for(int n = 0; n < 4; n++){
          int col = c0 + n * 16;
          float v = acc[m][n][j] + bv4[n];
          if(EPI == 1){
            // tanh-form GELU: x * sigmoid(2c(x + 0.044715 x^3)), 2c = 1.59576912
            float t = v * (1.5957691f + 0.07135481f * v * v);
            float gl = v * __builtin_amdgcn_rcpf(1.0f + __expf(-t));
            o0[(size_t)row * N + col] = f2bf(gl);
          } else if(EPI == 2){
            atomicAdd(&fout[(size_t)row * 768 + col], v);
          } else {
            atomicAdd(&fout[(size_t)row * 512 + col], v);
          }
        }
      }
    }
  }
}

// ---------------- BigBird attention, one block = (b, head, 128 queries) ----------------
// mask: allowed(i,j) = ((j<64) | (i-j<=32)) & (j<=i)
__global__ __launch_bounds__(256)
void k_attn(const unsigned short* __restrict__ qg, const unsigned short* __restrict__ kg,
            const unsigned short* __restrict__ vg, float* __restrict__ h){
  __shared__ unsigned short Vt[64 * 256];      // V^T [d][slot], 16B-chunk XOR swizzled
  __shared__ unsigned short Ps[4][32 * 128];   // per-wave P [32 q][128 slot], swizzled
  int qb = blockIdx.x, bh = blockIdx.y;
  int tid = threadIdx.x, w = tid >> 6, lane = tid & 63;
  int b = bh / 12, hd = bh - b * 12;
  int wbase = qb * 128 - 32;                   // first window key staged
  const unsigned short* vb = vg + (size_t)bh * 1024 * 64;
  for(int u = tid; u < 224 * 8; u += 256){
    int slot = u >> 3, c8 = u & 7;
    int j = slot < 64 ? slot : wbase + (slot - 64);
    if(j < 0) j = 0;
    short8 vv = *(const short8*)(vb + (size_t)j * 64 + c8 * 8);
    #pragma unroll
    for(int e = 0; e < 8; e++){
      int d = c8 * 8 + e;
      Vt[d * 256 + (((slot >> 3) ^ (d & 7)) << 3) + (slot & 7)] = (unsigned short)vv[e];
    }
  }
  __syncthreads();
  int i0 = qb * 128 + 32 * w;
  const unsigned short* qrow = qg + (size_t)bh * 1024 * 64;
  const unsigned short* krow = kg + (size_t)bh * 1024 * 64;
  short8 qf[2][2];
  #pragma unroll
  for(int m = 0; m < 2; m++)
    #pragma unroll
    for(int s = 0; s < 2; s++)
      qf[m][s] = *(const short8*)(qrow + (size_t)(i0 + m * 16 + (lane & 15)) * 64 + s * 32 + ((lane >> 4) << 3));
  f32x4 sacc[2][8] = {};
  #pragma unroll
  for(int n = 0; n < 8; n++){
    int jk = (n < 4) ? (n * 16 + (lane & 15))
                     : (wbase + 32 * w + (n - 4) * 16 + (lane & 15));
    int jc = jk < 0 ? 0 : jk;
    const unsigned short* kr = krow + (size_t)jc * 64 + ((lane >> 4) << 3);
    short8 k0 = *(const short8*)(kr);
    short8 k1 = *(const short8*)(kr + 32);
    #pragma unroll
    for(int m = 0; m < 2; m++){
      sacc[m][n] = __builtin_amdgcn_mfma_f32_16x16x32_bf16(qf[m][0], k0, sacc[m][n], 0, 0, 0);
      sacc[m][n] = __builtin_amdgcn_mfma_f32_16x16x32_bf16(qf[m][1], k1, sacc[m][n], 0, 0, 0);
    }
  }
  #pragma unroll
  for(int m = 0; m < 2; m++)
    #pragma unroll
    for(int n = 0; n < 8; n++){
      int s_ = n * 16 + (lane & 15);
      int jkey = (n < 4) ? s_ : (wbase + 32 * w + (s_ - 64));
      #pragma unroll
      for(int j = 0; j < 4; j++){
        int qi = i0 + m * 16 + ((lane >> 4) << 2) + j;
        bool ok = (n < 4) ? (jkey <= qi)
                          : (jkey >= 64 && jkey <= qi && (qi - jkey) <= 32);
        sacc[m][n][j] = ok ? sacc[m][n][j] * 0.125f : -1e30f;
      }
    }
  float rsum[2][4];
  #pragma unroll
  for(int m = 0; m < 2; m++)
    #pragma unroll
    for(int j = 0; j < 4; j++){
      float mx = sacc[m][0][j];
      #pragma unroll
      for(int n = 1; n < 8; n++) mx = fmaxf(mx, sacc[m][n][j]);
      mx = fmaxf(mx, __shfl_xor(mx, 1)); mx = fmaxf(mx, __shfl_xor(mx, 2));
      mx = fmaxf(mx, __shfl_xor(mx, 4)); mx = fmaxf(mx, __shfl_xor(mx, 8));
      float sm = 0.f;
      #pragma unroll
      for(int n = 0; n < 8; n++){
        float e = expf(sacc[m][n][j] - mx);
        sacc[m][n][j] = e;
        sm += e;
      }
      sm += __shfl_xor(sm, 1); sm += __shfl_xor(sm, 2);
      sm += __shfl_xor(sm, 4); sm += __shfl_xor(sm, 8);
      rsum[m][j] = sm;
    }
  unsigned short* Pw = Ps[w];
  #pragma unroll
  for(int m = 0; m < 2; m++)
    #pragma unroll
    for(int n = 0; n < 8; n++){
      int s_ = n * 16 + (lane & 15);
      #pragma unroll
      for(int j = 0; j < 4; j++){
        int ql = m * 16 + ((lane >> 4) << 2) + j;
        Pw[ql * 128 + (((s_ >> 3) ^ (ql & 7)) << 3) + (s_ & 7)] = f2bf(sacc[m][n][j]);
      }
    }
  f32x4 oacc[2][4] = {};
  #pragma unroll
  for(int s = 0; s < 4; s++){
    short8 pa[2];
    #pragma unroll
    for(int m = 0; m < 2; m++){
      int ql = m * 16 + (lane & 15);
      int ch = s * 4 + (lane >> 4);
      pa[m] = *(const short8*)(Pw + ql * 128 + ((ch ^ (ql & 7)) << 3));
    }
    int kk = s * 32 + ((lane >> 4) << 3);
    int slot0 = kk < 64 ? kk : 64 + 32 * w + (kk - 64);
    #pragma unroll
    for(int n = 0; n < 4; n++){
      int d = n * 16 + (lane & 15);
      short8 vv = *(const short8*)(Vt + d * 256 + (((slot0 >> 3) ^ (d & 7)) << 3));
      #pragma unroll
      for(int m = 0; m < 2; m++)
        oacc[m][n] = __builtin_amdgcn_mfma_f32_16x16x32_bf16(pa[m], vv, oacc[m][n], 0, 0, 0);
    }
  }
  #pragma unroll
  for(int m = 0; m < 2; m++)
    #pragma unroll
    for(int j = 0; j < 4; j++){
      int ql = m * 16 + ((lane >> 4) << 2) + j;
      float inv = 1.0f / rsum[m][j];
      size_t base = ((size_t)(b * 1024 + i0 + ql)) * 768 + hd * 64;
      #pragma unroll
      for(int n = 0; n < 4; n++){
        int d = n * 16 + (lane & 15);
        h[base + d] += oacc[m][n][j] * inv;
      }
    }
}

// ---------------- loss ----------------
__global__ void k_rowloss(const float* __restrict__ pred, const int* __restrict__ tgt,
                          float* __restrict__ rowloss){
  int row = blockIdx.x * 4 + (threadIdx.x >> 6);
  int lane = threadIdx.x & 63;
  const float* p = pred + (size_t)row * 512 + lane * 8;
  float v[8];
  #pragma unroll
  for(int i = 0; i < 8; i++) v[i] = p[i];
  float mx = v[0];
  #pragma unroll
  for(int i = 1; i < 8; i++) mx = fmaxf(mx, v[i]);
  #pragma unroll
  for(int m = 1; m < 64; m <<= 1) mx = fmaxf(mx, __shfl_xor(mx, m));
  float se = 0.f;
  #pragma unroll
  for(int i = 0; i < 8; i++) se += expf(v[i] - mx);
  #pragma unroll
  for(int m = 1; m < 64; m <<= 1) se += __shfl_xor(se, m);
  int t = tgt[row];
  float pt = 0.f;
  int base = lane * 8;
  #pragma unroll
  for(int i = 0; i < 8; i++) pt = (t == base + i) ? v[i] : pt;
  #pragma unroll
  for(int m = 1; m < 64; m <<= 1) pt += __shfl_xor(pt, m);
  if(lane == 0) rowloss[row] = -(pt - mx - logf(se));
}

__global__ void k_lossfinal(const float* __restrict__ rowloss, float* __restrict__ out){
  int tid = threadIdx.x;
  float s = 0.f;
  for(int i = tid; i < 8192; i += 256) s += rowloss[i];
  #pragma unroll
  for(int m = 32; m >= 1; m >>= 1) s += __shfl_xor(s, m);
  __shared__ float red[4];
  if((tid & 63) == 0) red[tid >> 6] = s;
  __syncthreads();
  if(tid == 0) out[0] = (red[0] + red[1] + red[2] + red[3]) * (1.0f / 8192.0f);
}

extern "C" void kernel_launch(void* const* d_in, const int* in_sizes, int n_in,
                              void* d_out, int out_size, void* d_ws, size_t ws_size,
                              hipStream_t stream){
  const int*   x       = (const int*)d_in[0];
  const int*   targets = (const int*)d_in[1];
  const float* wte     = (const float*)d_in[2];
  const float* pos     = (const float*)d_in[3];
  const float* ln1_g   = (const float*)d_in[4];
  const float* ln1_b   = (const float*)d_in[5];
  const float* wq      = (const float*)d_in[6];
  const float* bq      = (const float*)d_in[7];
  const float* wk      = (const float*)d_in[8];
  const float* bk      = (const float*)d_in[9];
  const float* wv      = (const float*)d_in[10];
  const float* bv      = (const float*)d_in[11];
  const float* ln2_g   = (const float*)d_in[12];
  const float* ln2_b   = (const float*)d_in[13];
  const float* w1      = (const float*)d_in[14];
  const float* b1      = (const float*)d_in[15];
  const float* w2      = (const float*)d_in[16];
  const float* b2      = (const float*)d_in[17];
  const float* lnf_g   = (const float*)d_in[18];
  const float* lnf_b   = (const float*)d_in[19];
  const float* w_out   = (const float*)d_in[20];
  float* out = (float*)d_out;

  char* ws = (char*)d_ws;
  float*          h      = (float*)ws;                              // 25,165,824 B
  unsigned short* a_bf   = (unsigned short*)(ws + 25165824);        // 12,582,912 B
  char*           big    = ws + 37748736;                           // 50,331,648 B (qkv | mlp-mid)
  unsigned short* qbf    = (unsigned short*)big;
  unsigned short* kbf    = (unsigned short*)(big + 12582912);
  unsigned short* vbf    = (unsigned short*)(big + 25165824);
  unsigned short* tbf    = (unsigned short*)big;
  char*           wb     = ws + 88080384;                           // per-layer bf16 weights
  unsigned short* wqkv_t = (unsigned short*)wb;                     // 3,538,944 B
  unsigned short* w1_t   = (unsigned short*)(wb + 3538944);         // 4,718,592 B
  unsigned short* w2_t   = (unsigned short*)(wb + 8257536);         // 4,718,592 B
  float*          qkvb   = (float*)(ws + 101056512);                // 9,216 B
  float*          rowls  = (float*)(ws + 101065728);                // 32,768 B

  k_embed<<<24576, 256, 0, stream>>>(x, wte, pos, h);
  for(int l = 0; l < 8; l++){
    k_convert_layer<<<6337, 256, 0, stream>>>(
        wq + (size_t)l * 589824, wk + (size_t)l * 589824, wv + (size_t)l * 589824,
        w1 + (size_t)l * 2359296, w2 + (size_t)l * 2359296,
        bq + l * 768, bk + l * 768, bv + l * 768, wqkv_t, w1_t, w2_t, qkvb);
    k_ln<<<8192, 256, 0, stream>>>(h, ln1_g + l * 768, ln1_b + l * 768, a_bf);
    k_gemm<0><<<dim3(18, 64), 256, 0, stream>>>(a_bf, wqkv_t, qkvb, 768, nullptr, qbf, kbf, vbf);
    k_attn<<<dim3(8, 96), 256, 0, stream>>>(qbf, kbf, vbf, h);
    k_ln<<<8192, 256, 0, stream>>>(h, ln2_g + l * 768, ln2_b + l * 768, a_bf);
    k_gemm<1><<<dim3(24, 64), 256, 0, stream>>>(a_bf, w1_t, b1 + l * 3072, 768, nullptr, tbf, nullptr, nullptr);
    k_gemm<2><<<dim3(6, 64, 2), 256, 0, stream>>>(tbf, w2_t, b2 + l * 768, 3072, h, nullptr, nullptr, nullptr);
  }
  k_ln<<<8192, 256, 0, stream>>>(h, lnf_g, lnf_b, a_bf);
  k_transpose<<<384, 256, 0, stream>>>(w_out, wqkv_t, 768, 512);    // reuse wqkv_t slot
  hipMemsetAsync(out, 0, (size_t)8192 * 512 * 4, stream);
  k_gemm<3><<<dim3(4, 64, 2), 256, 0, stream>>>(a_bf, wqkv_t, nullptr, 768, out, nullptr, nullptr, nullptr);
  k_rowloss<<<2048, 256, 0, stream>>>(out, targets, rowls);
  k_lossfinal<<<1, 256, 0, stream>>>(rowls, out + 4194304);
}

// Round 6
// 1619.267 us; speedup vs baseline: 1.1236x; 1.1236x over previous
//
#include <hip/hip_runtime.h>
#include <hip/hip_bf16.h>

#define DEV __device__ __forceinline__

typedef __attribute__((ext_vector_type(8))) short short8;
typedef __attribute__((ext_vector_type(4))) float f32x4;

DEV unsigned short f2bf(float f){
  unsigned int u = __builtin_bit_cast(unsigned int, f);
  u += 0x7FFFu + ((u >> 16) & 1u);
  return (unsigned short)(u >> 16);
}

DEV void gld_lds16(const void* g, void* l){
  __builtin_amdgcn_global_load_lds((const __attribute__((address_space(1))) void*)g,
                                   (__attribute__((address_space(3))) void*)l, 16, 0, 0);
}

// ---------------- embedding: h = wte[x] + pos ----------------
__global__ void k_embed(const int* __restrict__ x, const float* __restrict__ wte,
                        const float* __restrict__ pos, float* __restrict__ h){
  int i = blockIdx.x * 256 + threadIdx.x;           // total 8192*768
  int row = i / 768, d = i - row * 768;
  int s = row & 1023;
  h[i] = wte[x[row] * 768 + d] + pos[s * 768 + d];
}

// ---------------- layernorm (f32 in) -> bf16 out ----------------
__global__ void k_ln(const float* __restrict__ src, const float* __restrict__ g,
                     const float* __restrict__ b, unsigned short* __restrict__ out){
  int row = blockIdx.x, t = threadIdx.x;
  const float* p = src + (size_t)row * 768;
  float v0 = p[t], v1 = p[t + 256], v2 = p[t + 512];
  float s = v0 + v1 + v2;
  float sq = v0 * v0 + v1 * v1 + v2 * v2;
  #pragma unroll
  for(int m = 32; m >= 1; m >>= 1){ s += __shfl_xor(s, m); sq += __shfl_xor(sq, m); }
  __shared__ float red[8];
  int w = t >> 6;
  if((t & 63) == 0){ red[w] = s; red[4 + w] = sq; }
  __syncthreads();
  float S  = red[0] + red[1] + red[2] + red[3];
  float SQ = red[4] + red[5] + red[6] + red[7];
  float mu  = S * (1.0f / 768.0f);
  float var = SQ * (1.0f / 768.0f) - mu * mu;
  float inv = rsqrtf(var + 1e-5f);
  unsigned short* o = out + (size_t)row * 768;
  o[t]       = f2bf((v0 - mu) * inv * g[t]       + b[t]);
  o[t + 256] = f2bf((v1 - mu) * inv * g[t + 256] + b[t + 256]);
  o[t + 512] = f2bf((v2 - mu) * inv * g[t + 512] + b[t + 512]);
}

// ---------------- tiled transpose f32[R][C] -> bf16 dst[C][R] ----------------
DEV void tr_tile(float (*tl)[33], const float* __restrict__ src, unsigned short* __restrict__ dst,
                 int R, int C, int tx, int ty, int tid){
  int lx = tid & 31, ly = tid >> 5;                 // 32 x 8
  int r0 = ty * 32, c0 = tx * 32;
  #pragma unroll
  for(int i = 0; i < 4; i++) tl[ly + 8*i][lx] = src[(size_t)(r0 + ly + 8*i) * C + (c0 + lx)];
  __syncthreads();
  #pragma unroll
  for(int i = 0; i < 4; i++) dst[(size_t)(c0 + ly + 8*i) * R + (r0 + lx)] = f2bf(tl[lx][ly + 8*i]);
}

// all-layer (or single-layer fallback) weight conversion:
// wq/wk/wv -> wqkv_t[2304][768] bf16, w1 -> w1_t[3072][768], w2 -> w2_t[768][3072],
// qkv bias packed [2304]. blockIdx.y = layer - l0, writes slot blockIdx.y.
__global__ void k_convert_all(const float* __restrict__ wq, const float* __restrict__ wk,
                              const float* __restrict__ wv, const float* __restrict__ w1,
                              const float* __restrict__ w2, const float* __restrict__ bq,
                              const float* __restrict__ bk, const float* __restrict__ bv,
                              unsigned short* __restrict__ wall, float* __restrict__ qkvb,
                              int l0){
  __shared__ float tl[32][33];
  int l = l0 + blockIdx.y, slot = blockIdx.y;
  int bid = blockIdx.x, tid = threadIdx.x;
  unsigned short* wqkv_t = wall + (size_t)slot * 6488064;
  unsigned short* w1_t   = wqkv_t + 1769472;
  unsigned short* w2_t   = w1_t + 2359296;
  float* qb = qkvb + slot * 2304;
  const float* wq_l = wq + (size_t)l * 589824;
  const float* wk_l = wk + (size_t)l * 589824;
  const float* wv_l = wv + (size_t)l * 589824;
  const float* w1_l = w1 + (size_t)l * 2359296;
  const float* w2_l = w2 + (size_t)l * 2359296;
  if(bid < 1728){
    int which = bid / 576, t = bid - which * 576;   // 24x24 tiles of 768x768
    const float* src = which == 0 ? wq_l : which == 1 ? wk_l : wv_l;
    tr_tile(tl, src, wqkv_t + (size_t)which * 589824, 768, 768, t % 24, t / 24, tid);
  } else if(bid < 1728 + 2304){
    int t = bid - 1728;                             // 96x24 tiles of 768x3072
    tr_tile(tl, w1_l, w1_t, 768, 3072, t % 96, t / 96, tid);
  } else if(bid < 1728 + 4608){
    int t = bid - 4032;                             // 24x96 tiles of 3072x768
    tr_tile(tl, w2_l, w2_t, 3072, 768, t % 24, t / 24, tid);
  } else {
    for(int i = tid; i < 768; i += 256){
      qb[i] = bq[l * 768 + i]; qb[768 + i] = bk[l * 768 + i]; qb[1536 + i] = bv[l * 768 + i];
    }
  }
}

__global__ void k_transpose(const float* __restrict__ src, unsigned short* __restrict__ dst,
                            int R, int C){
  __shared__ float tl[32][33];
  int nx = C / 32;
  tr_tile(tl, src, dst, R, C, blockIdx.x % nx, blockIdx.x / nx, threadIdx.x);
}

// ---------------- bf16 GEMM: C[M,N] = A[M,K] * Bt[N,K]^T  (+ fused epilogue) ----------------
// m97 structure: BM=128, BN = NB*32 (NB=4 -> 128, NB=2 -> 64), BK=64, 4 waves (2x2),
// single-buffer 2-barrier loop, global_load_lds width 16 with pre-swizzled source.
// T1: XCD-chunked block swizzle (bm-major chunks per XCD; requires nwg%8==0).
// NB=2 halves per-wave output (64x32) -> grid doubles in N: fixes occupancy for small-N GEMMs.
// EPI 0: +bias, split into q/k/v [B*H, S, 64] bf16   (NB=4 only)
// EPI 1: +bias, fast GELU, bf16 out [M,N]
// EPI 2: +bias, h[row,col] += val (residual, plain RMW)
// EPI 3: f32 logits out [M,512]
template<int EPI, int NB>
__global__ __launch_bounds__(256)
void k_gemm(const unsigned short* __restrict__ A, const unsigned short* __restrict__ Bt,
            const float* __restrict__ bias, int K,
            float* __restrict__ fout, unsigned short* __restrict__ o0,
            unsigned short* __restrict__ o1, unsigned short* __restrict__ o2){
  __shared__ unsigned short As[128 * 64];
  __shared__ unsigned short Bs[128 * 64];      // NB=2 uses first 64*64
  int tid = threadIdx.x, w = tid >> 6, lane = tid & 63;
  int nbx = gridDim.x;
  int bid = blockIdx.y * nbx + blockIdx.x;
  int cpx = (nbx * gridDim.y) >> 3;
  int sid = (bid & 7) * cpx + (bid >> 3);       // XCD k owns sids [k*cpx,(k+1)*cpx)
  int bm = sid / nbx, bn = sid - bm * nbx;      // bm-major within chunk -> A-panel/XCD locality
  int N = nbx * NB * 32;
  int wr = w >> 1, wc = w & 1;
  f32x4 acc[4][NB] = {};
  // staging geometry: instr i covers LDS bytes [(i*4+w)*1024, +1024)
  int rowA[4], colA[4];
  #pragma unroll
  for(int i = 0; i < 4; i++){
    int o = ((i * 4 + w) << 10) + (lane << 4);
    int r = o >> 7;                 // tile row (128B rows)
    int ch = (o >> 4) & 7;          // LDS 16B chunk within row
    rowA[i] = r;
    colA[i] = ((ch ^ (r & 7)) << 3);  // source element offset (swizzled)
  }
  const size_t aBase = (size_t)bm * 128;
  const size_t bBase = (size_t)bn * (NB * 32);
  for(int kt = 0; kt < K; kt += 64){
    #pragma unroll
    for(int i = 0; i < 4; i++)
      gld_lds16(A + (aBase + rowA[i]) * K + kt + colA[i], (char*)As + ((i * 4 + w) << 10));
    #pragma unroll
    for(int i = 0; i < NB; i++)
      gld_lds16(Bt + (bBase + rowA[i]) * K + kt + colA[i], (char*)Bs + ((i * 4 + w) << 10));
    __syncthreads();
    #pragma unroll
    for(int s = 0; s < 2; s++){
      short8 af[4], bfr[NB];
      #pragma unroll
      for(int m = 0; m < 4; m++){
        int r = wr * 64 + m * 16 + (lane & 15);
        int ch = s * 4 + (lane >> 4);
        af[m] = *(const short8*)(As + r * 64 + ((ch ^ (r & 7)) << 3));
      }
      #pragma unroll
      for(int n = 0; n < NB; n++){
        int r = wc * (NB * 16) + n * 16 + (lane & 15);
        int ch = s * 4 + (lane >> 4);
        bfr[n] = *(const short8*)(Bs + r * 64 + ((ch ^ (r & 7)) << 3));
      }
      #pragma unroll
      for(int m = 0; m < 4; m++)
        #pragma unroll
        for(int n = 0; n < NB; n++)
          acc[m][n] = __builtin_amdgcn_mfma_f32_16x16x32_bf16(af[m], bfr[n], acc[m][n], 0, 0, 0);
    }
    __syncthreads();
  }
  int r0 = bm * 128 + wr * 64 + ((lane >> 4) << 2);
  int c0 = bn * (NB * 32) + wc * (NB * 16) + (lane & 15);
  if(EPI == 0){
    unsigned short* dstn[NB];
    float bvn[NB];
    #pragma unroll
    for(int n = 0; n < NB; n++){
      int col = c0 + n * 16;
      bvn[n] = bias[col];
      int which = col / 768, cc = col - which * 768;
      int hd = cc >> 6, dl = cc & 63;
      unsigned short* dst = which == 0 ? o0 : which == 1 ? o1 : o2;
      dstn[n] = dst + (size_t)hd * 65536 + dl;
    }
    #pragma unroll
    for(int m = 0; m < 4; m++){
      #pragma unroll
      for(int j = 0; j < 4; j++){
        int row = r0 + m * 16 + j;
        int bb = row >> 10, sp = row & 1023;
        size_t ro = ((size_t)bb * 12288 + sp) * 64;
        #pragma unroll
        for(int n = 0; n < NB; n++)
          dstn[n][ro] = f2bf(acc[m][n][j] + bvn[n]);
      }
    }
  } else {
    float bvn[NB];
    #pragma unroll
    for(int n = 0; n < NB; n++) bvn[n] = (EPI == 3) ? 0.0f : bias[c0 + n * 16];
    #pragma unroll
    for(int m = 0; m < 4; m++){
      #pragma unroll
      for(int j = 0; j < 4; j++){
        int row = r0 + m * 16 + j;
        #pragma unroll
        for(int n = 0; n < NB; n++){
          int col = c0 + n * 16;
          float v = acc[m][n][j] + bvn[n];
          if(EPI == 1){
            // tanh-form GELU: x * sigmoid(2c(x + 0.044715 x^3)), 2c = 1.59576912
            float t = v * (1.5957691f + 0.07135481f * v * v);
            float gl = v * __builtin_amdgcn_rcpf(1.0f + __expf(-t));
            o0[(size_t)row * N + col] = f2bf(gl);
          } else if(EPI == 2){
            fout[(size_t)row * 768 + col] += v;
          } else {
            fout[(size_t)row * 512 + col] = v;
          }
        }
      }
    }
  }
}

// ---------------- BigBird attention, one block = (b, head, 128 queries) ----------------
// mask: allowed(i,j) = ((j<64) | (i-j<=32)) & (j<=i)
__global__ __launch_bounds__(256)
void k_attn(const unsigned short* __restrict__ qg, const unsigned short* __restrict__ kg,
            const unsigned short* __restrict__ vg, float* __restrict__ h){
  __shared__ unsigned short Vt[64 * 256];      // V^T [d][slot], 16B-chunk XOR swizzled
  __shared__ unsigned short Ps[4][32 * 128];   // per-wave P [32 q][128 slot], swizzled
  int qb = blockIdx.x, bh = blockIdx.y;
  int tid = threadIdx.x, w = tid >> 6, lane = tid & 63;
  int b = bh / 12, hd = bh - b * 12;
  int wbase = qb * 128 - 32;                   // first window key staged
  const unsigned short* vb = vg + (size_t)bh * 1024 * 64;
  for(int u = tid; u < 224 * 8; u += 256){
    int slot = u >> 3, c8 = u & 7;
    int j = slot < 64 ? slot : wbase + (slot - 64);
    if(j < 0) j = 0;
    short8 vv = *(const short8*)(vb + (size_t)j * 64 + c8 * 8);
    #pragma unroll
    for(int e = 0; e < 8; e++){
      int d = c8 * 8 + e;
      Vt[d * 256 + (((slot >> 3) ^ (d & 7)) << 3) + (slot & 7)] = (unsigned short)vv[e];
    }
  }
  __syncthreads();
  int i0 = qb * 128 + 32 * w;
  const unsigned short* qrow = qg + (size_t)bh * 1024 * 64;
  const unsigned short* krow = kg + (size_t)bh * 1024 * 64;
  short8 qf[2][2];
  #pragma unroll
  for(int m = 0; m < 2; m++)
    #pragma unroll
    for(int s = 0; s < 2; s++)
      qf[m][s] = *(const short8*)(qrow + (size_t)(i0 + m * 16 + (lane & 15)) * 64 + s * 32 + ((lane >> 4) << 3));
  f32x4 sacc[2][8] = {};
  #pragma unroll
  for(int n = 0; n < 8; n++){
    int jk = (n < 4) ? (n * 16 + (lane & 15))
                     : (wbase + 32 * w + (n - 4) * 16 + (lane & 15));
    int jc = jk < 0 ? 0 : jk;
    const unsigned short* kr = krow + (size_t)jc * 64 + ((lane >> 4) << 3);
    short8 k0 = *(const short8*)(kr);
    short8 k1 = *(const short8*)(kr + 32);
    #pragma unroll
    for(int m = 0; m < 2; m++){
      sacc[m][n] = __builtin_amdgcn_mfma_f32_16x16x32_bf16(qf[m][0], k0, sacc[m][n], 0, 0, 0);
      sacc[m][n] = __builtin_amdgcn_mfma_f32_16x16x32_bf16(qf[m][1], k1, sacc[m][n], 0, 0, 0);
    }
  }
  #pragma unroll
  for(int m = 0; m < 2; m++)
    #pragma unroll
    for(int n = 0; n < 8; n++){
      int s_ = n * 16 + (lane & 15);
      int jkey = (n < 4) ? s_ : (wbase + 32 * w + (s_ - 64));
      #pragma unroll
      for(int j = 0; j < 4; j++){
        int qi = i0 + m * 16 + ((lane >> 4) << 2) + j;
        bool ok = (n < 4) ? (jkey <= qi)
                          : (jkey >= 64 && jkey <= qi && (qi - jkey) <= 32);
        sacc[m][n][j] = ok ? sacc[m][n][j] * 0.125f : -1e30f;
      }
    }
  float rsum[2][4];
  #pragma unroll
  for(int m = 0; m < 2; m++)
    #pragma unroll
    for(int j = 0; j < 4; j++){
      float mx = sacc[m][0][j];
      #pragma unroll
      for(int n = 1; n < 8; n++) mx = fmaxf(mx, sacc[m][n][j]);
      mx = fmaxf(mx, __shfl_xor(mx, 1)); mx = fmaxf(mx, __shfl_xor(mx, 2));
      mx = fmaxf(mx, __shfl_xor(mx, 4)); mx = fmaxf(mx, __shfl_xor(mx, 8));
      float sm = 0.f;
      #pragma unroll
      for(int n = 0; n < 8; n++){
        float e = expf(sacc[m][n][j] - mx);
        sacc[m][n][j] = e;
        sm += e;
      }
      sm += __shfl_xor(sm, 1); sm += __shfl_xor(sm, 2);
      sm += __shfl_xor(sm, 4); sm += __shfl_xor(sm, 8);
      rsum[m][j] = sm;
    }
  unsigned short* Pw = Ps[w];
  #pragma unroll
  for(int m = 0; m < 2; m++)
    #pragma unroll
    for(int n = 0; n < 8; n++){
      int s_ = n * 16 + (lane & 15);
      #pragma unroll
      for(int j = 0; j < 4; j++){
        int ql = m * 16 + ((lane >> 4) << 2) + j;
        Pw[ql * 128 + (((s_ >> 3) ^ (ql & 7)) << 3) + (s_ & 7)] = f2bf(sacc[m][n][j]);
      }
    }
  f32x4 oacc[2][4] = {};
  #pragma unroll
  for(int s = 0; s < 4; s++){
    short8 pa[2];
    #pragma unroll
    for(int m = 0; m < 2; m++){
      int ql = m * 16 + (lane & 15);
      int ch = s * 4 + (lane >> 4);
      pa[m] = *(const short8*)(Pw + ql * 128 + ((ch ^ (ql & 7)) << 3));
    }
    int kk = s * 32 + ((lane >> 4) << 3);
    int slot0 = kk < 64 ? kk : 64 + 32 * w + (kk - 64);
    #pragma unroll
    for(int n = 0; n < 4; n++){
      int d = n * 16 + (lane & 15);
      short8 vv = *(const short8*)(Vt + d * 256 + (((slot0 >> 3) ^ (d & 7)) << 3));
      #pragma unroll
      for(int m = 0; m < 2; m++)
        oacc[m][n] = __builtin_amdgcn_mfma_f32_16x16x32_bf16(pa[m], vv, oacc[m][n], 0, 0, 0);
    }
  }
  #pragma unroll
  for(int m = 0; m < 2; m++)
    #pragma unroll
    for(int j = 0; j < 4; j++){
      int ql = m * 16 + ((lane >> 4) << 2) + j;
      float inv = 1.0f / rsum[m][j];
      size_t base = ((size_t)(b * 1024 + i0 + ql)) * 768 + hd * 64;
      #pragma unroll
      for(int n = 0; n < 4; n++){
        int d = n * 16 + (lane & 15);
        h[base + d] += oacc[m][n][j] * inv;
      }
    }
}

// ---------------- loss ----------------
__global__ void k_rowloss(const float* __restrict__ pred, const int* __restrict__ tgt,
                          float* __restrict__ rowloss){
  int row = blockIdx.x * 4 + (threadIdx.x >> 6);
  int lane = threadIdx.x & 63;
  const float* p = pred + (size_t)row * 512 + lane * 8;
  float v[8];
  #pragma unroll
  for(int i = 0; i < 8; i++) v[i] = p[i];
  float mx = v[0];
  #pragma unroll
  for(int i = 1; i < 8; i++) mx = fmaxf(mx, v[i]);
  #pragma unroll
  for(int m = 1; m < 64; m <<= 1) mx = fmaxf(mx, __shfl_xor(mx, m));
  float se = 0.f;
  #pragma unroll
  for(int i = 0; i < 8; i++) se += expf(v[i] - mx);
  #pragma unroll
  for(int m = 1; m < 64; m <<= 1) se += __shfl_xor(se, m);
  int t = tgt[row];
  float pt = 0.f;
  int base = lane * 8;
  #pragma unroll
  for(int i = 0; i < 8; i++) pt = (t == base + i) ? v[i] : pt;
  #pragma unroll
  for(int m = 1; m < 64; m <<= 1) pt += __shfl_xor(pt, m);
  if(lane == 0) rowloss[row] = -(pt - mx - logf(se));
}

__global__ void k_lossfinal(const float* __restrict__ rowloss, float* __restrict__ out){
  int tid = threadIdx.x;
  float s = 0.f;
  for(int i = tid; i < 8192; i += 256) s += rowloss[i];
  #pragma unroll
  for(int m = 32; m >= 1; m >>= 1) s += __shfl_xor(s, m);
  __shared__ float red[4];
  if((tid & 63) == 0) red[tid >> 6] = s;
  __syncthreads();
  if(tid == 0) out[0] = (red[0] + red[1] + red[2] + red[3]) * (1.0f / 8192.0f);
}

extern "C" void kernel_launch(void* const* d_in, const int* in_sizes, int n_in,
                              void* d_out, int out_size, void* d_ws, size_t ws_size,
                              hipStream_t stream){
  const int*   x       = (const int*)d_in[0];
  const int*   targets = (const int*)d_in[1];
  const float* wte     = (const float*)d_in[2];
  const float* pos     = (const float*)d_in[3];
  const float* ln1_g   = (const float*)d_in[4];
  const float* ln1_b   = (const float*)d_in[5];
  const float* wq      = (const float*)d_in[6];
  const float* bq      = (const float*)d_in[7];
  const float* wk      = (const float*)d_in[8];
  const float* bk      = (const float*)d_in[9];
  const float* wv      = (const float*)d_in[10];
  const float* bv      = (const float*)d_in[11];
  const float* ln2_g   = (const float*)d_in[12];
  const float* ln2_b   = (const float*)d_in[13];
  const float* w1      = (const float*)d_in[14];
  const float* b1      = (const float*)d_in[15];
  const float* w2      = (const float*)d_in[16];
  const float* b2      = (const float*)d_in[17];
  const float* lnf_g   = (const float*)d_in[18];
  const float* lnf_b   = (const float*)d_in[19];
  const float* w_out   = (const float*)d_in[20];
  float* out = (float*)d_out;

  char* ws = (char*)d_ws;
  float*          h      = (float*)ws;                              // 25,165,824 B
  unsigned short* a_bf   = (unsigned short*)(ws + 25165824);        // 12,582,912 B
  char*           big    = ws + 37748736;                           // 50,331,648 B (qkv | mlp-mid)
  unsigned short* qbf    = (unsigned short*)big;
  unsigned short* kbf    = (unsigned short*)(big + 12582912);
  unsigned short* vbf    = (unsigned short*)(big + 25165824);
  unsigned short* tbf    = (unsigned short*)big;
  // weights: per-layer slot = 12,976,128 B (wqkv_t 3.54MB | w1_t 4.72MB | w2_t 4.72MB)
  bool mega = ws_size >= 192782336ull;              // all-8-layer conversion fits?
  unsigned short* wall   = (unsigned short*)(ws + 88080384);
  size_t wend = 88080384ull + (mega ? 103809024ull : 12976128ull);
  unsigned short* wout_t = (unsigned short*)(ws + wend);            // 786,432 B
  float*          qkvb   = (float*)(ws + wend + 786432);            // 9,216 or 73,728 B
  float*          rowls  = (float*)(ws + wend + 786432 + (mega ? 73728 : 9216));

  if(mega)
    k_convert_all<<<dim3(6337, 8), 256, 0, stream>>>(wq, wk, wv, w1, w2, bq, bk, bv,
                                                     wall, qkvb, 0);
  k_transpose<<<384, 256, 0, stream>>>(w_out, wout_t, 768, 512);
  k_embed<<<24576, 256, 0, stream>>>(x, wte, pos, h);
  for(int l = 0; l < 8; l++){
    if(!mega)
      k_convert_all<<<dim3(6337, 1), 256, 0, stream>>>(wq, wk, wv, w1, w2, bq, bk, bv,
                                                       wall, qkvb, l);
    int slot = mega ? l : 0;
    unsigned short* wqkv_l = wall + (size_t)slot * 6488064;
    unsigned short* w1_l   = wqkv_l + 1769472;
    unsigned short* w2_l   = w1_l + 2359296;
    float*          qkvb_l = qkvb + slot * 2304;
    k_ln<<<8192, 256, 0, stream>>>(h, ln1_g + l * 768, ln1_b + l * 768, a_bf);
    k_gemm<0,4><<<dim3(18, 64), 256, 0, stream>>>(a_bf, wqkv_l, qkvb_l, 768, nullptr, qbf, kbf, vbf);
    k_attn<<<dim3(8, 96), 256, 0, stream>>>(qbf, kbf, vbf, h);
    k_ln<<<8192, 256, 0, stream>>>(h, ln2_g + l * 768, ln2_b + l * 768, a_bf);
    k_gemm<1,4><<<dim3(24, 64), 256, 0, stream>>>(a_bf, w1_l, b1 + l * 3072, 768, nullptr, tbf, nullptr, nullptr);
    k_gemm<2,2><<<dim3(12, 64), 256, 0, stream>>>(tbf, w2_l, b2 + l * 768, 3072, h, nullptr, nullptr, nullptr);
  }
  k_ln<<<8192, 256, 0, stream>>>(h, lnf_g, lnf_b, a_bf);
  k_gemm<3,2><<<dim3(8, 64), 256, 0, stream>>>(a_bf, wout_t, nullptr, 768, out, nullptr, nullptr, nullptr);
  k_rowloss<<<2048, 256, 0, stream>>>(out, targets, rowls);
  k_lossfinal<<<1, 256, 0, stream>>>(rowls, out + 4194304);
}

// Round 7
// 1594.870 us; speedup vs baseline: 1.1408x; 1.0153x over previous
//
#include <hip/hip_runtime.h>
#include <hip/hip_bf16.h>

#define DEV __device__ __forceinline__

typedef __attribute__((ext_vector_type(8))) short short8;
typedef __attribute__((ext_vector_type(4))) float f32x4;

DEV unsigned short f2bf(float f){
  unsigned int u = __builtin_bit_cast(unsigned int, f);
  u += 0x7FFFu + ((u >> 16) & 1u);
  return (unsigned short)(u >> 16);
}

DEV void gld_lds16(const void* g, void* l){
  __builtin_amdgcn_global_load_lds((const __attribute__((address_space(1))) void*)g,
                                   (__attribute__((address_space(3))) void*)l, 16, 0, 0);
}

// ---------------- embedding: h = wte[x] + pos ----------------
__global__ void k_embed(const int* __restrict__ x, const float* __restrict__ wte,
                        const float* __restrict__ pos, float* __restrict__ h){
  int i = blockIdx.x * 256 + threadIdx.x;           // total 8192*768
  int row = i / 768, d = i - row * 768;
  int s = row & 1023;
  h[i] = wte[x[row] * 768 + d] + pos[s * 768 + d];
}

// ---------------- layernorm (f32 in) -> bf16 out ----------------
__global__ void k_ln(const float* __restrict__ src, const float* __restrict__ g,
                     const float* __restrict__ b, unsigned short* __restrict__ out){
  int row = blockIdx.x, t = threadIdx.x;
  const float* p = src + (size_t)row * 768;
  float v0 = p[t], v1 = p[t + 256], v2 = p[t + 512];
  float s = v0 + v1 + v2;
  float sq = v0 * v0 + v1 * v1 + v2 * v2;
  #pragma unroll
  for(int m = 32; m >= 1; m >>= 1){ s += __shfl_xor(s, m); sq += __shfl_xor(sq, m); }
  __shared__ float red[8];
  int w = t >> 6;
  if((t & 63) == 0){ red[w] = s; red[4 + w] = sq; }
  __syncthreads();
  float S  = red[0] + red[1] + red[2] + red[3];
  float SQ = red[4] + red[5] + red[6] + red[7];
  float mu  = S * (1.0f / 768.0f);
  float var = SQ * (1.0f / 768.0f) - mu * mu;
  float inv = rsqrtf(var + 1e-5f);
  unsigned short* o = out + (size_t)row * 768;
  o[t]       = f2bf((v0 - mu) * inv * g[t]       + b[t]);
  o[t + 256] = f2bf((v1 - mu) * inv * g[t + 256] + b[t + 256]);
  o[t + 512] = f2bf((v2 - mu) * inv * g[t + 512] + b[t + 512]);
}

// ------- tiled transpose f32 src[R][C] -> bf16 dst[C][R], 64x32 tiles, ushort2 stores -------
DEV void tr_tile64(float (*tl)[33], const float* __restrict__ src, unsigned short* __restrict__ dst,
                   int R, int C, int tx, int ty, int tid){
  int lx = tid & 31, ly = tid >> 5;                 // 32 x 8
  int r0 = ty * 64, c0 = tx * 32;
  #pragma unroll
  for(int i = 0; i < 8; i++)
    tl[ly + 8 * i][lx] = src[(size_t)(r0 + ly + 8 * i) * C + (c0 + lx)];
  __syncthreads();
  #pragma unroll
  for(int j = 0; j < 4; j++){
    int oc = ly + 8 * j;
    unsigned int pk = (unsigned int)f2bf(tl[2 * lx][oc]) |
                      ((unsigned int)f2bf(tl[2 * lx + 1][oc]) << 16);
    *(unsigned int*)(dst + (size_t)(c0 + oc) * R + r0 + 2 * lx) = pk;
  }
}

// all-layer (or single-layer fallback) weight conversion:
// wq/wk/wv -> wqkv_t[2304][768] bf16, w1 -> w1_t[3072][768], w2 -> w2_t[768][3072],
// qkv bias packed [2304]. blockIdx.y = layer - l0, writes slot blockIdx.y.
// sections (64x32 tiles): qkv 3*(12*24)=864 | w1 12*96=1152 | w2 48*24=1152 | bias 1 -> 3169
__global__ void k_convert_all(const float* __restrict__ wq, const float* __restrict__ wk,
                              const float* __restrict__ wv, const float* __restrict__ w1,
                              const float* __restrict__ w2, const float* __restrict__ bq,
                              const float* __restrict__ bk, const float* __restrict__ bv,
                              unsigned short* __restrict__ wall, float* __restrict__ qkvb,
                              int l0){
  __shared__ float tl[64][33];
  int l = l0 + blockIdx.y, slot = blockIdx.y;
  int bid = blockIdx.x, tid = threadIdx.x;
  unsigned short* wqkv_t = wall + (size_t)slot * 6488064;
  unsigned short* w1_t   = wqkv_t + 1769472;
  unsigned short* w2_t   = w1_t + 2359296;
  float* qb = qkvb + slot * 2304;
  const float* wq_l = wq + (size_t)l * 589824;
  const float* wk_l = wk + (size_t)l * 589824;
  const float* wv_l = wv + (size_t)l * 589824;
  const float* w1_l = w1 + (size_t)l * 2359296;
  const float* w2_l = w2 + (size_t)l * 2359296;
  if(bid < 864){
    int which = bid / 288, t = bid - which * 288;   // 12 ty x 24 tx tiles of 768x768
    const float* src = which == 0 ? wq_l : which == 1 ? wk_l : wv_l;
    tr_tile64(tl, src, wqkv_t + (size_t)which * 589824, 768, 768, t % 24, t / 24, tid);
  } else if(bid < 864 + 1152){
    int t = bid - 864;                              // 12 ty x 96 tx tiles of 768x3072
    tr_tile64(tl, w1_l, w1_t, 768, 3072, t % 96, t / 96, tid);
  } else if(bid < 864 + 2304){
    int t = bid - 2016;                             // 48 ty x 24 tx tiles of 3072x768
    tr_tile64(tl, w2_l, w2_t, 3072, 768, t % 24, t / 24, tid);
  } else {
    for(int i = tid; i < 768; i += 256){
      qb[i] = bq[l * 768 + i]; qb[768 + i] = bk[l * 768 + i]; qb[1536 + i] = bv[l * 768 + i];
    }
  }
}

__global__ void k_transpose(const float* __restrict__ src, unsigned short* __restrict__ dst,
                            int R, int C){
  __shared__ float tl[64][33];
  int nx = C / 32;
  tr_tile64(tl, src, dst, R, C, blockIdx.x % nx, blockIdx.x / nx, threadIdx.x);
}

// ---------------- bf16 GEMM: C[M,N] = A[M,K] * Bt[N,K]^T  (+ fused epilogue) ----------------
// m97 loop; tile BM = MW*64 rows x BN = NB*32 cols, MW*2 waves (MW rows x 2 cols of waves),
// per-wave 64 x NB*16. BK=64, single-buffer 2-barrier, global_load_lds w=16, T2 pre-swizzled
// source, T1 XCD-chunked block swizzle (requires nwg%8==0).
// MW=4 (512 thr, 48KB LDS): high MACs/staged-byte for the big-N GEMMs.
// MW=2 NB=2 (256 thr, 24KB): occupancy-friendly for small-N (MLP2, logits).
// EPI 0: +bias, split q/k/v [B*H,S,64] bf16 | 1: +bias fast-GELU bf16 | 2: +bias h+= | 3: f32 out
template<int EPI, int MW, int NB>
__global__ __launch_bounds__(MW * 128, 4)
void k_gemm(const unsigned short* __restrict__ A, const unsigned short* __restrict__ Bt,
            const float* __restrict__ bias, int K,
            float* __restrict__ fout, unsigned short* __restrict__ o0,
            unsigned short* __restrict__ o1, unsigned short* __restrict__ o2){
  constexpr int THREADS = MW * 128;
  constexpr int AL = 4;                 // A gld_lds per thread
  constexpr int BL = (2 * NB) / MW;     // B gld_lds per thread
  __shared__ unsigned short As[MW * 64 * 64];
  __shared__ unsigned short Bs[NB * 32 * 64];
  int tid = threadIdx.x, w = tid >> 6, lane = tid & 63;
  int l15 = lane & 15, l4 = lane >> 4;
  int nbx = gridDim.x;
  int bid = blockIdx.y * nbx + blockIdx.x;
  int cpx = (nbx * gridDim.y) >> 3;
  int sid = (bid & 7) * cpx + (bid >> 3);       // XCD k owns sids [k*cpx,(k+1)*cpx)
  int bm = sid / nbx, bn = sid - bm * nbx;      // bm-major within chunk -> A-panel/XCD locality
  int N = nbx * NB * 32;
  int wr = w >> 1, wc = w & 1;
  f32x4 acc[4][NB] = {};
  int rowA[AL], colA[AL], rowB[BL], colB[BL];
  #pragma unroll
  for(int i = 0; i < AL; i++){
    int o = i * THREADS * 16 + tid * 16;
    int r = o >> 7, ch = (o >> 4) & 7;
    rowA[i] = r; colA[i] = ((ch ^ (r & 7)) << 3);
  }
  #pragma unroll
  for(int i = 0; i < BL; i++){
    int o = i * THREADS * 16 + tid * 16;
    int r = o >> 7, ch = (o >> 4) & 7;
    rowB[i] = r; colB[i] = ((ch ^ (r & 7)) << 3);
  }
  const size_t aBase = (size_t)bm * (MW * 64);
  const size_t bBase = (size_t)bn * (NB * 32);
  for(int kt = 0; kt < K; kt += 64){
    #pragma unroll
    for(int i = 0; i < AL; i++)
      gld_lds16(A + (aBase + rowA[i]) * K + kt + colA[i],
                (char*)As + i * THREADS * 16 + tid * 16);
    #pragma unroll
    for(int i = 0; i < BL; i++)
      gld_lds16(Bt + (bBase + rowB[i]) * K + kt + colB[i],
                (char*)Bs + i * THREADS * 16 + tid * 16);
    __syncthreads();
    #pragma unroll
    for(int s = 0; s < 2; s++){
      short8 af[4], bfr[NB];
      #pragma unroll
      for(int m = 0; m < 4; m++){
        int r = wr * 64 + m * 16 + l15;
        int ch = s * 4 + l4;
        af[m] = *(const short8*)(As + r * 64 + ((ch ^ (r & 7)) << 3));
      }
      #pragma unroll
      for(int n = 0; n < NB; n++){
        int r = wc * (NB * 16) + n * 16 + l15;
        int ch = s * 4 + l4;
        bfr[n] = *(const short8*)(Bs + r * 64 + ((ch ^ (r & 7)) << 3));
      }
      #pragma unroll
      for(int m = 0; m < 4; m++)
        #pragma unroll
        for(int n = 0; n < NB; n++)
          acc[m][n] = __builtin_amdgcn_mfma_f32_16x16x32_bf16(af[m], bfr[n], acc[m][n], 0, 0, 0);
    }
    __syncthreads();
  }
  int r0 = bm * (MW * 64) + wr * 64 + (l4 << 2);
  int c0 = bn * (NB * 32) + wc * (NB * 16) + l15;
  if(EPI == 0){
    unsigned short* dstn[NB];
    float bvn[NB];
    #pragma unroll
    for(int n = 0; n < NB; n++){
      int col = c0 + n * 16;
      bvn[n] = bias[col];
      int which = col / 768, cc = col - which * 768;
      int hd = cc >> 6, dl = cc & 63;
      unsigned short* dst = which == 0 ? o0 : which == 1 ? o1 : o2;
      dstn[n] = dst + (size_t)hd * 65536 + dl;
    }
    #pragma unroll
    for(int m = 0; m < 4; m++){
      #pragma unroll
      for(int j = 0; j < 4; j++){
        int row = r0 + m * 16 + j;
        int bb = row >> 10, sp = row & 1023;
        size_t ro = ((size_t)bb * 12288 + sp) * 64;
        #pragma unroll
        for(int n = 0; n < NB; n++)
          dstn[n][ro] = f2bf(acc[m][n][j] + bvn[n]);
      }
    }
  } else {
    float bvn[NB];
    #pragma unroll
    for(int n = 0; n < NB; n++) bvn[n] = (EPI == 3) ? 0.0f : bias[c0 + n * 16];
    #pragma unroll
    for(int m = 0; m < 4; m++){
      #pragma unroll
      for(int j = 0; j < 4; j++){
        int row = r0 + m * 16 + j;
        #pragma unroll
        for(int n = 0; n < NB; n++){
          int col = c0 + n * 16;
          float v = acc[m][n][j] + bvn[n];
          if(EPI == 1){
            // tanh-form GELU: x * sigmoid(2c(x + 0.044715 x^3)), 2c = 1.59576912
            float t = v * (1.5957691f + 0.07135481f * v * v);
            float gl = v * __builtin_amdgcn_rcpf(1.0f + __expf(-t));
            o0[(size_t)row * N + col] = f2bf(gl);
          } else if(EPI == 2){
            fout[(size_t)row * 768 + col] += v;
          } else {
            fout[(size_t)row * 512 + col] = v;
          }
        }
      }
    }
  }
}

// ---------------- BigBird attention, one block = (b, head, 128 queries) ----------------
// mask: allowed(i,j) = ((j<64) | (i-j<=32)) & (j<=i)
__global__ __launch_bounds__(256)
void k_attn(const unsigned short* __restrict__ qg, const unsigned short* __restrict__ kg,
            const unsigned short* __restrict__ vg, float* __restrict__ h){
  __shared__ unsigned short Vt[64 * 256];      // V^T [d][slot], 16B-chunk XOR swizzled
  __shared__ unsigned short Ps[4][32 * 128];   // per-wave P [32 q][128 slot], swizzled
  int qb = blockIdx.x, bh = blockIdx.y;
  int tid = threadIdx.x, w = tid >> 6, lane = tid & 63;
  int b = bh / 12, hd = bh - b * 12;
  int wbase = qb * 128 - 32;                   // first window key staged
  const unsigned short* vb = vg + (size_t)bh * 1024 * 64;
  for(int u = tid; u < 224 * 8; u += 256){
    int slot = u >> 3, c8 = u & 7;
    int j = slot < 64 ? slot : wbase + (slot - 64);
    if(j < 0) j = 0;
    short8 vv = *(const short8*)(vb + (size_t)j * 64 + c8 * 8);
    #pragma unroll
    for(int e = 0; e < 8; e++){
      int d = c8 * 8 + e;
      Vt[d * 256 + (((slot >> 3) ^ (d & 7)) << 3) + (slot & 7)] = (unsigned short)vv[e];
    }
  }
  __syncthreads();
  int i0 = qb * 128 + 32 * w;
  const unsigned short* qrow = qg + (size_t)bh * 1024 * 64;
  const unsigned short* krow = kg + (size_t)bh * 1024 * 64;
  short8 qf[2][2];
  #pragma unroll
  for(int m = 0; m < 2; m++)
    #pragma unroll
    for(int s = 0; s < 2; s++)
      qf[m][s] = *(const short8*)(qrow + (size_t)(i0 + m * 16 + (lane & 15)) * 64 + s * 32 + ((lane >> 4) << 3));
  f32x4 sacc[2][8] = {};
  #pragma unroll
  for(int n = 0; n < 8; n++){
    int jk = (n < 4) ? (n * 16 + (lane & 15))
                     : (wbase + 32 * w + (n - 4) * 16 + (lane & 15));
    int jc = jk < 0 ? 0 : jk;
    const unsigned short* kr = krow + (size_t)jc * 64 + ((lane >> 4) << 3);
    short8 k0 = *(const short8*)(kr);
    short8 k1 = *(const short8*)(kr + 32);
    #pragma unroll
    for(int m = 0; m < 2; m++){
      sacc[m][n] = __builtin_amdgcn_mfma_f32_16x16x32_bf16(qf[m][0], k0, sacc[m][n], 0, 0, 0);
      sacc[m][n] = __builtin_amdgcn_mfma_f32_16x16x32_bf16(qf[m][1], k1, sacc[m][n], 0, 0, 0);
    }
  }
  #pragma unroll
  for(int m = 0; m < 2; m++)
    #pragma unroll
    for(int n = 0; n < 8; n++){
      int s_ = n * 16 + (lane & 15);
      int jkey = (n < 4) ? s_ : (wbase + 32 * w + (s_ - 64));
      #pragma unroll
      for(int j = 0; j < 4; j++){
        int qi = i0 + m * 16 + ((lane >> 4) << 2) + j;
        bool ok = (n < 4) ? (jkey <= qi)
                          : (jkey >= 64 && jkey <= qi && (qi - jkey) <= 32);
        sacc[m][n][j] = ok ? sacc[m][n][j] * 0.125f : -1e30f;
      }
    }
  float rsum[2][4];
  #pragma unroll
  for(int m = 0; m < 2; m++)
    #pragma unroll
    for(int j = 0; j < 4; j++){
      float mx = sacc[m][0][j];
      #pragma unroll
      for(int n = 1; n < 8; n++) mx = fmaxf(mx, sacc[m][n][j]);
      mx = fmaxf(mx, __shfl_xor(mx, 1)); mx = fmaxf(mx, __shfl_xor(mx, 2));
      mx = fmaxf(mx, __shfl_xor(mx, 4)); mx = fmaxf(mx, __shfl_xor(mx, 8));
      float sm = 0.f;
      #pragma unroll
      for(int n = 0; n < 8; n++){
        float e = expf(sacc[m][n][j] - mx);
        sacc[m][n][j] = e;
        sm += e;
      }
      sm += __shfl_xor(sm, 1); sm += __shfl_xor(sm, 2);
      sm += __shfl_xor(sm, 4); sm += __shfl_xor(sm, 8);
      rsum[m][j] = sm;
    }
  unsigned short* Pw = Ps[w];
  #pragma unroll
  for(int m = 0; m < 2; m++)
    #pragma unroll
    for(int n = 0; n < 8; n++){
      int s_ = n * 16 + (lane & 15);
      #pragma unroll
      for(int j = 0; j < 4; j++){
        int ql = m * 16 + ((lane >> 4) << 2) + j;
        Pw[ql * 128 + (((s_ >> 3) ^ (ql & 7)) << 3) + (s_ & 7)] = f2bf(sacc[m][n][j]);
      }
    }
  f32x4 oacc[2][4] = {};
  #pragma unroll
  for(int s = 0; s < 4; s++){
    short8 pa[2];
    #pragma unroll
    for(int m = 0; m < 2; m++){
      int ql = m * 16 + (lane & 15);
      int ch = s * 4 + (lane >> 4);
      pa[m] = *(const short8*)(Pw + ql * 128 + ((ch ^ (ql & 7)) << 3));
    }
    int kk = s * 32 + ((lane >> 4) << 3);
    int slot0 = kk < 64 ? kk : 64 + 32 * w + (kk - 64);
    #pragma unroll
    for(int n = 0; n < 4; n++){
      int d = n * 16 + (lane & 15);
      short8 vv = *(const short8*)(Vt + d * 256 + (((slot0 >> 3) ^ (d & 7)) << 3));
      #pragma unroll
      for(int m = 0; m < 2; m++)
        oacc[m][n] = __builtin_amdgcn_mfma_f32_16x16x32_bf16(pa[m], vv, oacc[m][n], 0, 0, 0);
    }
  }
  #pragma unroll
  for(int m = 0; m < 2; m++)
    #pragma unroll
    for(int j = 0; j < 4; j++){
      int ql = m * 16 + ((lane >> 4) << 2) + j;
      float inv = 1.0f / rsum[m][j];
      size_t base = ((size_t)(b * 1024 + i0 + ql)) * 768 + hd * 64;
      #pragma unroll
      for(int n = 0; n < 4; n++){
        int d = n * 16 + (lane & 15);
        h[base + d] += oacc[m][n][j] * inv;
      }
    }
}

// ---------------- loss ----------------
__global__ void k_rowloss(const float* __restrict__ pred, const int* __restrict__ tgt,
                          float* __restrict__ rowloss){
  int row = blockIdx.x * 4 + (threadIdx.x >> 6);
  int lane = threadIdx.x & 63;
  const float* p = pred + (size_t)row * 512 + lane * 8;
  float v[8];
  #pragma unroll
  for(int i = 0; i < 8; i++) v[i] = p[i];
  float mx = v[0];
  #pragma unroll
  for(int i = 1; i < 8; i++) mx = fmaxf(mx, v[i]);
  #pragma unroll
  for(int m = 1; m < 64; m <<= 1) mx = fmaxf(mx, __shfl_xor(mx, m));
  float se = 0.f;
  #pragma unroll
  for(int i = 0; i < 8; i++) se += expf(v[i] - mx);
  #pragma unroll
  for(int m = 1; m < 64; m <<= 1) se += __shfl_xor(se, m);
  int t = tgt[row];
  float pt = 0.f;
  int base = lane * 8;
  #pragma unroll
  for(int i = 0; i < 8; i++) pt = (t == base + i) ? v[i] : pt;
  #pragma unroll
  for(int m = 1; m < 64; m <<= 1) pt += __shfl_xor(pt, m);
  if(lane == 0) rowloss[row] = -(pt - mx - logf(se));
}

__global__ void k_lossfinal(const float* __restrict__ rowloss, float* __restrict__ out){
  int tid = threadIdx.x;
  float s = 0.f;
  for(int i = tid; i < 8192; i += 256) s += rowloss[i];
  #pragma unroll
  for(int m = 32; m >= 1; m >>= 1) s += __shfl_xor(s, m);
  __shared__ float red[4];
  if((tid & 63) == 0) red[tid >> 6] = s;
  __syncthreads();
  if(tid == 0) out[0] = (red[0] + red[1] + red[2] + red[3]) * (1.0f / 8192.0f);
}

extern "C" void kernel_launch(void* const* d_in, const int* in_sizes, int n_in,
                              void* d_out, int out_size, void* d_ws, size_t ws_size,
                              hipStream_t stream){
  const int*   x       = (const int*)d_in[0];
  const int*   targets = (const int*)d_in[1];
  const float* wte     = (const float*)d_in[2];
  const float* pos     = (const float*)d_in[3];
  const float* ln1_g   = (const float*)d_in[4];
  const float* ln1_b   = (const float*)d_in[5];
  const float* wq      = (const float*)d_in[6];
  const float* bq      = (const float*)d_in[7];
  const float* wk      = (const float*)d_in[8];
  const float* bk      = (const float*)d_in[9];
  const float* wv      = (const float*)d_in[10];
  const float* bv      = (const float*)d_in[11];
  const float* ln2_g   = (const float*)d_in[12];
  const float* ln2_b   = (const float*)d_in[13];
  const float* w1      = (const float*)d_in[14];
  const float* b1      = (const float*)d_in[15];
  const float* w2      = (const float*)d_in[16];
  const float* b2      = (const float*)d_in[17];
  const float* lnf_g   = (const float*)d_in[18];
  const float* lnf_b   = (const float*)d_in[19];
  const float* w_out   = (const float*)d_in[20];
  float* out = (float*)d_out;

  char* ws = (char*)d_ws;
  float*          h      = (float*)ws;                              // 25,165,824 B
  unsigned short* a_bf   = (unsigned short*)(ws + 25165824);        // 12,582,912 B
  char*           big    = ws + 37748736;                           // 50,331,648 B (qkv | mlp-mid)
  unsigned short* qbf    = (unsigned short*)big;
  unsigned short* kbf    = (unsigned short*)(big + 12582912);
  unsigned short* vbf    = (unsigned short*)(big + 25165824);
  unsigned short* tbf    = (unsigned short*)big;
  // weights: per-layer slot = 12,976,128 B (wqkv_t 3.54MB | w1_t 4.72MB | w2_t 4.72MB)
  bool mega = ws_size >= 192782336ull;              // all-8-layer conversion fits?
  unsigned short* wall   = (unsigned short*)(ws + 88080384);
  size_t wend = 88080384ull + (mega ? 103809024ull : 12976128ull);
  unsigned short* wout_t = (unsigned short*)(ws + wend);            // 786,432 B
  float*          qkvb   = (float*)(ws + wend + 786432);            // 9,216 or 73,728 B
  float*          rowls  = (float*)(ws + wend + 786432 + (mega ? 73728 : 9216));

  if(mega)
    k_convert_all<<<dim3(3169, 8), 256, 0, stream>>>(wq, wk, wv, w1, w2, bq, bk, bv,
                                                     wall, qkvb, 0);
  k_transpose<<<192, 256, 0, stream>>>(w_out, wout_t, 768, 512);    // 12 ty x 16 tx
  k_embed<<<24576, 256, 0, stream>>>(x, wte, pos, h);
  for(int l = 0; l < 8; l++){
    if(!mega)
      k_convert_all<<<dim3(3169, 1), 256, 0, stream>>>(wq, wk, wv, w1, w2, bq, bk, bv,
                                                       wall, qkvb, l);
    int slot = mega ? l : 0;
    unsigned short* wqkv_l = wall + (size_t)slot * 6488064;
    unsigned short* w1_l   = wqkv_l + 1769472;
    unsigned short* w2_l   = w1_l + 2359296;
    float*          qkvb_l = qkvb + slot * 2304;
    k_ln<<<8192, 256, 0, stream>>>(h, ln1_g + l * 768, ln1_b + l * 768, a_bf);
    k_gemm<0,4,4><<<dim3(18, 32), 512, 0, stream>>>(a_bf, wqkv_l, qkvb_l, 768, nullptr, qbf, kbf, vbf);
    k_attn<<<dim3(8, 96), 256, 0, stream>>>(qbf, kbf, vbf, h);
    k_ln<<<8192, 256, 0, stream>>>(h, ln2_g + l * 768, ln2_b + l * 768, a_bf);
    k_gemm<1,4,4><<<dim3(24, 32), 512, 0, stream>>>(a_bf, w1_l, b1 + l * 3072, 768, nullptr, tbf, nullptr, nullptr);
    k_gemm<2,2,2><<<dim3(12, 64), 256, 0, stream>>>(tbf, w2_l, b2 + l * 768, 3072, h, nullptr, nullptr, nullptr);
  }
  k_ln<<<8192, 256, 0, stream>>>(h, lnf_g, lnf_b, a_bf);
  k_gemm<3,2,2><<<dim3(8, 64), 256, 0, stream>>>(a_bf, wout_t, nullptr, 768, out, nullptr, nullptr, nullptr);
  k_rowloss<<<2048, 256, 0, stream>>>(out, targets, rowls);
  k_lossfinal<<<1, 256, 0, stream>>>(rowls, out + 4194304);
}